// Round 4
// baseline (3817.165 us; speedup 1.0000x reference)
//
#include <hip/hip_runtime.h>

#define NB 8
#define NPTS 8192
#define NC_FEAT 64
#define NS 2048
#define NK 32

// Exact reference arithmetic for squared distance: no fma contraction,
// sum association ((dx^2 + dy^2) + dz^2) to match XLA's linear reduce.
__device__ __forceinline__ float d2_ref(float px, float py, float pz,
                                        float qx, float qy, float qz) {
  float dx = __fsub_rn(px, qx);
  float dy = __fsub_rn(py, qy);
  float dz = __fsub_rn(pz, qz);
  return __fadd_rn(__fadd_rn(__fmul_rn(dx, dx), __fmul_rn(dy, dy)),
                   __fmul_rn(dz, dz));
}

// ---------------------------------------------------------------------------
// Kernel 1: blocks 0..7  = FPS (one block per batch)
//           blocks 8..1031 = feature transpose (B,C,N)->(B,N,C) tiles
//           block 1032   = weight transpose to [c][o] layout
// ---------------------------------------------------------------------------
__global__ __launch_bounds__(1024)
void k_fps_tp(const float* __restrict__ pos, const float* __restrict__ feat,
              const float* __restrict__ w0, const float* __restrict__ w1,
              const float* __restrict__ w2,
              float* __restrict__ new_xyz, float* __restrict__ featT,
              float* __restrict__ wT) {
  __shared__ float smem[3 * NPTS + 64];  // 96.25 KB
  const int tid = threadIdx.x;

  if (blockIdx.x < NB) {
    // ------------------------- FPS -------------------------
    const int b = blockIdx.x;
    float* sx = smem;
    float* sy = smem + NPTS;
    float* sz = smem + 2 * NPTS;
    float* rbd = smem + 3 * NPTS;          // [2][16] partial max dist
    int* rbi = (int*)(smem + 3 * NPTS + 32);  // [2][16] partial argmax

    const float* p = pos + (size_t)b * NPTS * 3;
    for (int i = tid; i < NPTS; i += 1024) {
      sx[i] = p[3 * i + 0];
      sy[i] = p[3 * i + 1];
      sz[i] = p[3 * i + 2];
    }
    __syncthreads();

    float px[8], py[8], pz[8], dist[8];
#pragma unroll
    for (int j = 0; j < 8; ++j) {
      int idx = tid * 8 + j;
      px[j] = sx[idx]; py[j] = sy[idx]; pz[j] = sz[idx];
      dist[j] = 1e10f;
    }
    if (tid == 0) {
      new_xyz[((size_t)b * NS) * 3 + 0] = sx[0];
      new_xyz[((size_t)b * NS) * 3 + 1] = sy[0];
      new_xyz[((size_t)b * NS) * 3 + 2] = sz[0];
    }

    const int lane = tid & 63;
    const int wave = tid >> 6;
    int last = 0, buf = 0;

    for (int it = 1; it < NS; ++it) {
      float qx = sx[last], qy = sy[last], qz = sz[last];
      float bd = -1.0f;
      int bi = 0x7fffffff;
#pragma unroll
      for (int j = 0; j < 8; ++j) {
        float d = d2_ref(px[j], py[j], pz[j], qx, qy, qz);
        float nd = fminf(dist[j], d);
        dist[j] = nd;
        if (nd > bd) { bd = nd; bi = tid * 8 + j; }
      }
      // wave-level butterfly argmax (lowest index wins ties = first-occurrence)
#pragma unroll
      for (int m = 32; m >= 1; m >>= 1) {
        float od = __shfl_xor(bd, m, 64);
        int oi = __shfl_xor(bi, m, 64);
        if (od > bd || (od == bd && oi < bi)) { bd = od; bi = oi; }
      }
      if (lane == 0) { rbd[buf * 16 + wave] = bd; rbi[buf * 16 + wave] = bi; }
      __syncthreads();
      // all waves redundantly reduce the 16 partials (no second barrier;
      // double-buffered rbd/rbi)
      float fd = rbd[buf * 16 + (lane & 15)];
      int fi = rbi[buf * 16 + (lane & 15)];
#pragma unroll
      for (int m = 8; m >= 1; m >>= 1) {
        float od = __shfl_xor(fd, m, 64);
        int oi = __shfl_xor(fi, m, 64);
        if (od > fd || (od == fd && oi < fi)) { fd = od; fi = oi; }
      }
      last = fi;
      buf ^= 1;
      if (tid == 0) {
        new_xyz[((size_t)b * NS + it) * 3 + 0] = sx[fi];
        new_xyz[((size_t)b * NS + it) * 3 + 1] = sy[fi];
        new_xyz[((size_t)b * NS + it) * 3 + 2] = sz[fi];
      }
    }
  } else if (blockIdx.x < NB + NB * (NPTS / 64)) {
    // --------------------- feature transpose ---------------------
    const int t = blockIdx.x - NB;
    const int b = t >> 7;            // t / 128
    const int n0 = (t & 127) << 6;   // *64
    float* tile = smem;              // [64][65]
    const int col = tid & 63;
    const int r0 = tid >> 6;  // 0..15
#pragma unroll
    for (int q = 0; q < 4; ++q) {
      int c = r0 + q * 16;
      tile[c * 65 + col] = feat[((size_t)b * NC_FEAT + c) * NPTS + n0 + col];
    }
    __syncthreads();
#pragma unroll
    for (int q = 0; q < 4; ++q) {
      int r = r0 + q * 16;
      featT[((size_t)b * NPTS + n0 + r) * 64 + col] = tile[col * 65 + r];
    }
  } else {
    // --------------------- weight transpose ---------------------
    for (int i = tid; i < 67 * 64; i += 1024)
      wT[i] = w0[(i & 63) * 67 + (i >> 6)];
    for (int i = tid; i < 64 * 64; i += 1024)
      wT[67 * 64 + i] = w1[(i & 63) * 64 + (i >> 6)];
    for (int i = tid; i < 64 * 128; i += 1024)
      wT[67 * 64 + 64 * 64 + i] = w2[(i & 127) * 64 + (i >> 7)];
  }
}

// ---------------------------------------------------------------------------
// Kernel 2: ball query. One wave per query point; first-32-hits via ballot.
// ---------------------------------------------------------------------------
__global__ __launch_bounds__(256)
void k_ball(const float* __restrict__ pos, const float* __restrict__ nxyz,
            int* __restrict__ ballidx) {
  const int wid = (blockIdx.x * 256 + threadIdx.x) >> 6;  // global wave id
  const int lane = threadIdx.x & 63;
  const int b = wid >> 11;
  const float qx = nxyz[wid * 3 + 0];
  const float qy = nxyz[wid * 3 + 1];
  const float qz = nxyz[wid * 3 + 2];
  const float* p = pos + (size_t)b * NPTS * 3;
  int* outp = ballidx + (size_t)wid * NK;

  int cnt = 0;
  int firstidx = 0x7fffffff;
  for (int n0 = 0; n0 < NPTS; n0 += 64) {
    const int i = n0 + lane;
    float d2 = d2_ref(p[3 * i], p[3 * i + 1], p[3 * i + 2], qx, qy, qz);
    bool hit = d2 < 0.25f;
    unsigned long long mask = __ballot(hit);
    int pre = __popcll(mask & ((1ull << lane) - 1ull));
    int slot = cnt + pre;
    if (hit && slot < NK) outp[slot] = i;
    if (hit && slot == 0) firstidx = i;
    cnt += __popcll(mask);
    if (cnt >= NK) break;
  }
#pragma unroll
  for (int m = 32; m >= 1; m >>= 1)
    firstidx = min(firstidx, __shfl_xor(firstidx, m, 64));
  int pad = (firstidx == 0x7fffffff) ? 0 : firstidx;
  int start = cnt < NK ? cnt : NK;
  if (lane < NK && lane >= start) outp[lane] = pad;
}

// ---------------------------------------------------------------------------
// Kernel 3: gather + 3-layer MLP + max over k. One thread per (b,s,k) sample.
// Per-thread column in LDS (stride 256 -> conflict-free), weights read as
// wave-uniform float4 broadcasts from pre-transposed wT.
// ---------------------------------------------------------------------------
#define MLP_FMA16(wr, xc, acc)                                   \
  _Pragma("unroll") for (int o4 = 0; o4 < 16; ++o4) {            \
    float4 w = (wr)[o4];                                         \
    (acc)[o4 * 4 + 0] = fmaf(w.x, (xc), (acc)[o4 * 4 + 0]);      \
    (acc)[o4 * 4 + 1] = fmaf(w.y, (xc), (acc)[o4 * 4 + 1]);      \
    (acc)[o4 * 4 + 2] = fmaf(w.z, (xc), (acc)[o4 * 4 + 2]);      \
    (acc)[o4 * 4 + 3] = fmaf(w.w, (xc), (acc)[o4 * 4 + 3]);      \
  }

__global__ __launch_bounds__(256)
void k_mlp(const float* __restrict__ pos, const float* __restrict__ featT,
           const float* __restrict__ wT, const float* __restrict__ b0,
           const float* __restrict__ b1, const float* __restrict__ b2,
           const int* __restrict__ ballidx, const float* __restrict__ nxyz,
           float* __restrict__ outf) {
  __shared__ float xs[64 * 256];  // 64 KB: per-thread column, stride 256
  const int tid = threadIdx.x;
  const int g = blockIdx.x * 256 + tid;
  const int s = (g >> 5) & (NS - 1);
  const int b = g >> 16;

  const int idx = ballidx[g];
  const float qx = nxyz[((size_t)b * NS + s) * 3 + 0];
  const float qy = nxyz[((size_t)b * NS + s) * 3 + 1];
  const float qz = nxyz[((size_t)b * NS + s) * 3 + 2];
  const float* pp = pos + ((size_t)b * NPTS + idx) * 3;
  const float x0 = __fsub_rn(pp[0], qx);
  const float x1 = __fsub_rn(pp[1], qy);
  const float x2 = __fsub_rn(pp[2], qz);

  const float4* fT = (const float4*)(featT + ((size_t)b * NPTS + idx) * 64);
#pragma unroll
  for (int c4 = 0; c4 < 16; ++c4) {
    float4 v = fT[c4];
    xs[(c4 * 4 + 0) * 256 + tid] = v.x;
    xs[(c4 * 4 + 1) * 256 + tid] = v.y;
    xs[(c4 * 4 + 2) * 256 + tid] = v.z;
    xs[(c4 * 4 + 3) * 256 + tid] = v.w;
  }

  const float* wt0 = wT;
  const float* wt1 = wT + 67 * 64;
  const float* wt2 = wT + 67 * 64 + 64 * 64;

  float acc[64];
  // ---------------- layer 0: 67 -> 64 ----------------
#pragma unroll
  for (int o = 0; o < 64; ++o) acc[o] = b0[o];
  {
    const float xr0 = x0, xr1 = x1, xr2 = x2;
    const float4* wr;
    wr = (const float4*)(wt0 + 0 * 64); MLP_FMA16(wr, xr0, acc);
    wr = (const float4*)(wt0 + 1 * 64); MLP_FMA16(wr, xr1, acc);
    wr = (const float4*)(wt0 + 2 * 64); MLP_FMA16(wr, xr2, acc);
  }
  for (int c = 0; c < 64; ++c) {
    float xc = xs[c * 256 + tid];
    const float4* wr = (const float4*)(wt0 + (3 + c) * 64);
    MLP_FMA16(wr, xc, acc);
  }
#pragma unroll
  for (int o = 0; o < 64; ++o) xs[o * 256 + tid] = fmaxf(acc[o], 0.0f);

  // ---------------- layer 1: 64 -> 64 ----------------
#pragma unroll
  for (int o = 0; o < 64; ++o) acc[o] = b1[o];
  for (int c = 0; c < 64; ++c) {
    float xc = xs[c * 256 + tid];
    const float4* wr = (const float4*)(wt1 + c * 64);
    MLP_FMA16(wr, xc, acc);
  }
#pragma unroll
  for (int o = 0; o < 64; ++o) xs[o * 256 + tid] = fmaxf(acc[o], 0.0f);

  // ---------------- layer 2: 64 -> 128 (two halves) + max over k ----------
#pragma unroll
  for (int h = 0; h < 2; ++h) {
#pragma unroll
    for (int o = 0; o < 64; ++o) acc[o] = b2[h * 64 + o];
    for (int c = 0; c < 64; ++c) {
      float xc = xs[c * 256 + tid];
      const float4* wr = (const float4*)(wt2 + c * 128 + h * 64);
      MLP_FMA16(wr, xc, acc);
    }
#pragma unroll
    for (int o = 0; o < 64; ++o) {
      float v = fmaxf(acc[o], 0.0f);
      v = fmaxf(v, __shfl_xor(v, 16, 64));
      v = fmaxf(v, __shfl_xor(v, 8, 64));
      v = fmaxf(v, __shfl_xor(v, 4, 64));
      v = fmaxf(v, __shfl_xor(v, 2, 64));
      v = fmaxf(v, __shfl_xor(v, 1, 64));
      if ((tid & 31) == 0)
        outf[((size_t)b * 128 + h * 64 + o) * NS + s] = v;
    }
  }
}

// ---------------------------------------------------------------------------
extern "C" void kernel_launch(void* const* d_in, const int* in_sizes, int n_in,
                              void* d_out, int out_size, void* d_ws,
                              size_t ws_size, hipStream_t stream) {
  const float* pos = (const float*)d_in[0];
  const float* feat = (const float*)d_in[1];
  const float* w0 = (const float*)d_in[2];
  const float* b0 = (const float*)d_in[3];
  const float* w1 = (const float*)d_in[4];
  const float* b1 = (const float*)d_in[5];
  const float* w2 = (const float*)d_in[6];
  const float* b2 = (const float*)d_in[7];

  float* out = (float*)d_out;
  float* new_xyz = out;                         // (B, S, 3)
  float* new_feat = out + (size_t)NB * NS * 3;  // (B, 128, S)

  int* ballidx = (int*)d_ws;                                    // B*S*K ints
  float* featT = (float*)d_ws + (size_t)NB * NS * NK;           // B*N*64
  float* wT = featT + (size_t)NB * NPTS * 64;                   // 16576 floats

  // FPS (blocks 0..7) + feature transpose (1024 blocks) + weight transpose
  hipLaunchKernelGGL(k_fps_tp, dim3(NB + NB * (NPTS / 64) + 1), dim3(1024), 0,
                     stream, pos, feat, w0, w1, w2, new_xyz, featT, wT);
  // ball query: one wave per (b,s)
  hipLaunchKernelGGL(k_ball, dim3((NB * NS) / 4), dim3(256), 0, stream, pos,
                     new_xyz, ballidx);
  // gather + MLP + max-k
  hipLaunchKernelGGL(k_mlp, dim3((NB * NS * NK) / 256), dim3(256), 0, stream,
                     pos, featT, wT, b0, b1, b2, ballidx, new_xyz, new_feat);
}

// Round 5
// 2588.244 us; speedup vs baseline: 1.4748x; 1.4748x over previous
//
#include <hip/hip_runtime.h>

#define NB 8
#define NPTS 8192
#define NC_FEAT 64
#define NS 2048
#define NK 32

// Exact reference arithmetic for squared distance: no fma contraction,
// sum association ((dx^2 + dy^2) + dz^2) to match XLA's linear reduce.
__device__ __forceinline__ float d2_ref(float px, float py, float pz,
                                        float qx, float qy, float qz) {
  float dx = __fsub_rn(px, qx);
  float dy = __fsub_rn(py, qy);
  float dz = __fsub_rn(pz, qz);
  return __fadd_rn(__fadd_rn(__fmul_rn(dx, dx), __fmul_rn(dy, dy)),
                   __fmul_rn(dz, dz));
}

// DPP max-combine step on a packed u64 key (dist_bits<<32 | ~idx).
// v_mov_b32_dpp (VALU, ~2-4cyc) replaces ds_bpermute (~120cyc LDS latency).
// bound_ctrl=true -> out-of-range lanes contribute key 0 (< any real key).
#define DPP_KEYMAX(key, ctrl)                                                 \
  {                                                                           \
    unsigned _lo = (unsigned)__builtin_amdgcn_update_dpp(                     \
        0, (int)(unsigned)(key), (ctrl), 0xf, 0xf, true);                     \
    unsigned _hi = (unsigned)__builtin_amdgcn_update_dpp(                     \
        0, (int)(unsigned)((key) >> 32), (ctrl), 0xf, 0xf, true);             \
    unsigned long long _o = ((unsigned long long)_hi << 32) | _lo;            \
    if (_o > (key)) (key) = _o;                                               \
  }

// ---------------------------------------------------------------------------
// Kernel 1: blocks 0..7  = FPS (one block per batch)
//           blocks 8..1031 = feature transpose (B,C,N)->(B,N,C) tiles
//           block 1032   = weight transpose to [c][o] layout
// ---------------------------------------------------------------------------
__global__ __launch_bounds__(1024)
void k_fps_tp(const float* __restrict__ pos, const float* __restrict__ feat,
              const float* __restrict__ w0, const float* __restrict__ w1,
              const float* __restrict__ w2,
              float* __restrict__ new_xyz, float* __restrict__ featT,
              float* __restrict__ wT) {
  __shared__ __align__(16) float smem[3 * NPTS + 64];  // 96.25 KB
  const int tid = threadIdx.x;

  if (blockIdx.x < NB) {
    // ------------------------- FPS -------------------------
    const int b = blockIdx.x;
    float* sx = smem;
    float* sy = smem + NPTS;
    float* sz = smem + 2 * NPTS;
    // double-buffered per-wave winning keys: u64[2][16] at 8B-aligned offset
    unsigned long long* rk = (unsigned long long*)(smem + 3 * NPTS);

    const float* p = pos + (size_t)b * NPTS * 3;
    for (int i = tid; i < NPTS; i += 1024) {
      sx[i] = p[3 * i + 0];
      sy[i] = p[3 * i + 1];
      sz[i] = p[3 * i + 2];
    }
    __syncthreads();

    float px[8], py[8], pz[8], dist[8];
#pragma unroll
    for (int j = 0; j < 8; ++j) {
      int idx = tid * 8 + j;
      px[j] = sx[idx]; py[j] = sy[idx]; pz[j] = sz[idx];
      dist[j] = 1e10f;
    }
    if (tid == 0) {
      new_xyz[((size_t)b * NS) * 3 + 0] = sx[0];
      new_xyz[((size_t)b * NS) * 3 + 1] = sy[0];
      new_xyz[((size_t)b * NS) * 3 + 2] = sz[0];
    }

    const int lane = tid & 63;
    const int wave = tid >> 6;
    int last = 0, buf = 0;

    for (int it = 1; it < NS; ++it) {
      float qx = sx[last], qy = sy[last], qz = sz[last];
      float bd = -1.0f;
      int bj = 0;
#pragma unroll
      for (int j = 0; j < 8; ++j) {
        float d = d2_ref(px[j], py[j], pz[j], qx, qy, qz);
        float nd = fminf(dist[j], d);
        dist[j] = nd;
        if (nd > bd) { bd = nd; bj = j; }  // strict > : first j wins ties
      }
      // pack (dist, index): u64 max == lexicographic (dist, -idx) max.
      // dist >= 0 so uint compare of float bits == float compare.
      unsigned gidx = (unsigned)(tid * 8 + bj);
      unsigned long long key =
          ((unsigned long long)__float_as_uint(bd) << 32) | (unsigned)~gidx;
      // wave-level max via DPP: row_shr 1/2/4/8 then bcast15/bcast31 -> lane63
      DPP_KEYMAX(key, 0x111);
      DPP_KEYMAX(key, 0x112);
      DPP_KEYMAX(key, 0x114);
      DPP_KEYMAX(key, 0x118);
      DPP_KEYMAX(key, 0x142);
      DPP_KEYMAX(key, 0x143);
      if (lane == 63) rk[buf * 16 + wave] = key;
      __syncthreads();
      // cross-wave: 16 keys; rows of 16 lanes each hold all 16 -> 4 DPP steps
      // reduce into lane 15 of each row (double-buffered rk, single barrier).
      key = rk[buf * 16 + (lane & 15)];
      DPP_KEYMAX(key, 0x111);
      DPP_KEYMAX(key, 0x112);
      DPP_KEYMAX(key, 0x114);
      DPP_KEYMAX(key, 0x118);
      int fi = (int)~(unsigned)__builtin_amdgcn_readlane((int)(unsigned)key, 15);
      last = fi;
      buf ^= 1;
      if (tid == 0) {
        new_xyz[((size_t)b * NS + it) * 3 + 0] = sx[fi];
        new_xyz[((size_t)b * NS + it) * 3 + 1] = sy[fi];
        new_xyz[((size_t)b * NS + it) * 3 + 2] = sz[fi];
      }
    }
  } else if (blockIdx.x < NB + NB * (NPTS / 64)) {
    // --------------------- feature transpose ---------------------
    const int t = blockIdx.x - NB;
    const int b = t >> 7;            // t / 128
    const int n0 = (t & 127) << 6;   // *64
    float* tile = smem;              // [64][65]
    const int col = tid & 63;
    const int r0 = tid >> 6;  // 0..15
#pragma unroll
    for (int q = 0; q < 4; ++q) {
      int c = r0 + q * 16;
      tile[c * 65 + col] = feat[((size_t)b * NC_FEAT + c) * NPTS + n0 + col];
    }
    __syncthreads();
#pragma unroll
    for (int q = 0; q < 4; ++q) {
      int r = r0 + q * 16;
      featT[((size_t)b * NPTS + n0 + r) * 64 + col] = tile[col * 65 + r];
    }
  } else {
    // --------------------- weight transpose ---------------------
    for (int i = tid; i < 67 * 64; i += 1024)
      wT[i] = w0[(i & 63) * 67 + (i >> 6)];
    for (int i = tid; i < 64 * 64; i += 1024)
      wT[67 * 64 + i] = w1[(i & 63) * 64 + (i >> 6)];
    for (int i = tid; i < 64 * 128; i += 1024)
      wT[67 * 64 + 64 * 64 + i] = w2[(i & 127) * 64 + (i >> 7)];
  }
}

// ---------------------------------------------------------------------------
// Kernel 2: ball query. One wave per query point; first-32-hits via ballot.
// ---------------------------------------------------------------------------
__global__ __launch_bounds__(256)
void k_ball(const float* __restrict__ pos, const float* __restrict__ nxyz,
            int* __restrict__ ballidx) {
  const int wid = (blockIdx.x * 256 + threadIdx.x) >> 6;  // global wave id
  const int lane = threadIdx.x & 63;
  const int b = wid >> 11;
  const float qx = nxyz[wid * 3 + 0];
  const float qy = nxyz[wid * 3 + 1];
  const float qz = nxyz[wid * 3 + 2];
  const float* p = pos + (size_t)b * NPTS * 3;
  int* outp = ballidx + (size_t)wid * NK;

  int cnt = 0;
  int firstidx = 0x7fffffff;
  for (int n0 = 0; n0 < NPTS; n0 += 64) {
    const int i = n0 + lane;
    float d2 = d2_ref(p[3 * i], p[3 * i + 1], p[3 * i + 2], qx, qy, qz);
    bool hit = d2 < 0.25f;
    unsigned long long mask = __ballot(hit);
    int pre = __popcll(mask & ((1ull << lane) - 1ull));
    int slot = cnt + pre;
    if (hit && slot < NK) outp[slot] = i;
    if (hit && slot == 0) firstidx = i;
    cnt += __popcll(mask);
    if (cnt >= NK) break;
  }
#pragma unroll
  for (int m = 32; m >= 1; m >>= 1)
    firstidx = min(firstidx, __shfl_xor(firstidx, m, 64));
  int pad = (firstidx == 0x7fffffff) ? 0 : firstidx;
  int start = cnt < NK ? cnt : NK;
  if (lane < NK && lane >= start) outp[lane] = pad;
}

// ---------------------------------------------------------------------------
// Kernel 3: gather + 3-layer MLP + max over k. One thread per (b,s,k) sample.
// Per-thread column in LDS (stride 256 -> conflict-free), weights read as
// wave-uniform float4 broadcasts from pre-transposed wT.
// ---------------------------------------------------------------------------
#define MLP_FMA16(wr, xc, acc)                                   \
  _Pragma("unroll") for (int o4 = 0; o4 < 16; ++o4) {            \
    float4 w = (wr)[o4];                                         \
    (acc)[o4 * 4 + 0] = fmaf(w.x, (xc), (acc)[o4 * 4 + 0]);      \
    (acc)[o4 * 4 + 1] = fmaf(w.y, (xc), (acc)[o4 * 4 + 1]);      \
    (acc)[o4 * 4 + 2] = fmaf(w.z, (xc), (acc)[o4 * 4 + 2]);      \
    (acc)[o4 * 4 + 3] = fmaf(w.w, (xc), (acc)[o4 * 4 + 3]);      \
  }

__global__ __launch_bounds__(256)
void k_mlp(const float* __restrict__ pos, const float* __restrict__ featT,
           const float* __restrict__ wT, const float* __restrict__ b0,
           const float* __restrict__ b1, const float* __restrict__ b2,
           const int* __restrict__ ballidx, const float* __restrict__ nxyz,
           float* __restrict__ outf) {
  __shared__ float xs[64 * 256];  // 64 KB: per-thread column, stride 256
  const int tid = threadIdx.x;
  const int g = blockIdx.x * 256 + tid;
  const int s = (g >> 5) & (NS - 1);
  const int b = g >> 16;

  const int idx = ballidx[g];
  const float qx = nxyz[((size_t)b * NS + s) * 3 + 0];
  const float qy = nxyz[((size_t)b * NS + s) * 3 + 1];
  const float qz = nxyz[((size_t)b * NS + s) * 3 + 2];
  const float* pp = pos + ((size_t)b * NPTS + idx) * 3;
  const float x0 = __fsub_rn(pp[0], qx);
  const float x1 = __fsub_rn(pp[1], qy);
  const float x2 = __fsub_rn(pp[2], qz);

  const float4* fT = (const float4*)(featT + ((size_t)b * NPTS + idx) * 64);
#pragma unroll
  for (int c4 = 0; c4 < 16; ++c4) {
    float4 v = fT[c4];
    xs[(c4 * 4 + 0) * 256 + tid] = v.x;
    xs[(c4 * 4 + 1) * 256 + tid] = v.y;
    xs[(c4 * 4 + 2) * 256 + tid] = v.z;
    xs[(c4 * 4 + 3) * 256 + tid] = v.w;
  }

  const float* wt0 = wT;
  const float* wt1 = wT + 67 * 64;
  const float* wt2 = wT + 67 * 64 + 64 * 64;

  float acc[64];
  // ---------------- layer 0: 67 -> 64 ----------------
#pragma unroll
  for (int o = 0; o < 64; ++o) acc[o] = b0[o];
  {
    const float xr0 = x0, xr1 = x1, xr2 = x2;
    const float4* wr;
    wr = (const float4*)(wt0 + 0 * 64); MLP_FMA16(wr, xr0, acc);
    wr = (const float4*)(wt0 + 1 * 64); MLP_FMA16(wr, xr1, acc);
    wr = (const float4*)(wt0 + 2 * 64); MLP_FMA16(wr, xr2, acc);
  }
  for (int c = 0; c < 64; ++c) {
    float xc = xs[c * 256 + tid];
    const float4* wr = (const float4*)(wt0 + (3 + c) * 64);
    MLP_FMA16(wr, xc, acc);
  }
#pragma unroll
  for (int o = 0; o < 64; ++o) xs[o * 256 + tid] = fmaxf(acc[o], 0.0f);

  // ---------------- layer 1: 64 -> 64 ----------------
#pragma unroll
  for (int o = 0; o < 64; ++o) acc[o] = b1[o];
  for (int c = 0; c < 64; ++c) {
    float xc = xs[c * 256 + tid];
    const float4* wr = (const float4*)(wt1 + c * 64);
    MLP_FMA16(wr, xc, acc);
  }
#pragma unroll
  for (int o = 0; o < 64; ++o) xs[o * 256 + tid] = fmaxf(acc[o], 0.0f);

  // ---------------- layer 2: 64 -> 128 (two halves) + max over k ----------
#pragma unroll
  for (int h = 0; h < 2; ++h) {
#pragma unroll
    for (int o = 0; o < 64; ++o) acc[o] = b2[h * 64 + o];
    for (int c = 0; c < 64; ++c) {
      float xc = xs[c * 256 + tid];
      const float4* wr = (const float4*)(wt2 + c * 128 + h * 64);
      MLP_FMA16(wr, xc, acc);
    }
#pragma unroll
    for (int o = 0; o < 64; ++o) {
      float v = fmaxf(acc[o], 0.0f);
      v = fmaxf(v, __shfl_xor(v, 16, 64));
      v = fmaxf(v, __shfl_xor(v, 8, 64));
      v = fmaxf(v, __shfl_xor(v, 4, 64));
      v = fmaxf(v, __shfl_xor(v, 2, 64));
      v = fmaxf(v, __shfl_xor(v, 1, 64));
      if ((tid & 31) == 0)
        outf[((size_t)b * 128 + h * 64 + o) * NS + s] = v;
    }
  }
}

// ---------------------------------------------------------------------------
extern "C" void kernel_launch(void* const* d_in, const int* in_sizes, int n_in,
                              void* d_out, int out_size, void* d_ws,
                              size_t ws_size, hipStream_t stream) {
  const float* pos = (const float*)d_in[0];
  const float* feat = (const float*)d_in[1];
  const float* w0 = (const float*)d_in[2];
  const float* b0 = (const float*)d_in[3];
  const float* w1 = (const float*)d_in[4];
  const float* b1 = (const float*)d_in[5];
  const float* w2 = (const float*)d_in[6];
  const float* b2 = (const float*)d_in[7];

  float* out = (float*)d_out;
  float* new_xyz = out;                         // (B, S, 3)
  float* new_feat = out + (size_t)NB * NS * 3;  // (B, 128, S)

  int* ballidx = (int*)d_ws;                                    // B*S*K ints
  float* featT = (float*)d_ws + (size_t)NB * NS * NK;           // B*N*64
  float* wT = featT + (size_t)NB * NPTS * 64;                   // 16576 floats

  // FPS (blocks 0..7) + feature transpose (1024 blocks) + weight transpose
  hipLaunchKernelGGL(k_fps_tp, dim3(NB + NB * (NPTS / 64) + 1), dim3(1024), 0,
                     stream, pos, feat, w0, w1, w2, new_xyz, featT, wT);
  // ball query: one wave per (b,s)
  hipLaunchKernelGGL(k_ball, dim3((NB * NS) / 4), dim3(256), 0, stream, pos,
                     new_xyz, ballidx);
  // gather + MLP + max-k
  hipLaunchKernelGGL(k_mlp, dim3((NB * NS * NK) / 256), dim3(256), 0, stream,
                     pos, featT, wT, b0, b1, b2, ballidx, new_xyz, new_feat);
}

// Round 6
// 2456.974 us; speedup vs baseline: 1.5536x; 1.0534x over previous
//
#include <hip/hip_runtime.h>

#define NB 8
#define NPTS 8192
#define NC_FEAT 64
#define NS 2048
#define NK 32

typedef float v2f __attribute__((ext_vector_type(2)));

// Exact reference arithmetic for squared distance: no fma contraction,
// sum association ((dx^2 + dy^2) + dz^2) to match XLA's linear reduce.
__device__ __forceinline__ float d2_ref(float px, float py, float pz,
                                        float qx, float qy, float qz) {
  float dx = __fsub_rn(px, qx);
  float dy = __fsub_rn(py, qy);
  float dz = __fsub_rn(pz, qz);
  return __fadd_rn(__fadd_rn(__fmul_rn(dx, dx), __fmul_rn(dy, dy)),
                   __fmul_rn(dz, dz));
}

// DPP max-combine step on a packed u64 key (dist_bits<<32 | ~idx).
// bound_ctrl=true -> out-of-range lanes contribute key 0 (< any real key).
#define DPP_KEYMAX(key, ctrl)                                                 \
  {                                                                           \
    unsigned _lo = (unsigned)__builtin_amdgcn_update_dpp(                     \
        0, (int)(unsigned)(key), (ctrl), 0xf, 0xf, true);                     \
    unsigned _hi = (unsigned)__builtin_amdgcn_update_dpp(                     \
        0, (int)(unsigned)((key) >> 32), (ctrl), 0xf, 0xf, true);             \
    unsigned long long _o = ((unsigned long long)_hi << 32) | _lo;            \
    if (_o > (key)) (key) = _o;                                               \
  }

// ---------------------------------------------------------------------------
// Kernel 0: FPS, one 512-thread block per batch, 16 pts/lane as 8 v2f pairs.
// Issue-bound -> packed fp32 ops + minimal per-iteration bookkeeping.
// ---------------------------------------------------------------------------
__global__ __launch_bounds__(512)
void k_fps(const float* __restrict__ pos, float* __restrict__ new_xyz) {
#pragma clang fp contract(off)
  __shared__ __align__(16) float smem[3 * NPTS + 64];  // pos + u64 keys[2][16]
  const int tid = threadIdx.x;
  const int b = blockIdx.x;
  float* sx = smem;
  float* sy = smem + NPTS;
  float* sz = smem + 2 * NPTS;
  unsigned long long* rk = (unsigned long long*)(smem + 3 * NPTS);

  const float* p = pos + (size_t)b * NPTS * 3;
  for (int i = tid; i < NPTS; i += 512) {
    sx[i] = p[3 * i + 0];
    sy[i] = p[3 * i + 1];
    sz[i] = p[3 * i + 2];
  }
  if (tid < 32) rk[tid] = 0ull;  // zero both buffers; slots 8..15 stay 0
  __syncthreads();

  const int base = tid * 16;
  v2f px[8], py[8], pz[8], di[8];
#pragma unroll
  for (int k = 0; k < 8; ++k) {
    px[k] = (v2f){sx[base + 2 * k], sx[base + 2 * k + 1]};
    py[k] = (v2f){sy[base + 2 * k], sy[base + 2 * k + 1]};
    pz[k] = (v2f){sz[base + 2 * k], sz[base + 2 * k + 1]};
    di[k] = (v2f){1e10f, 1e10f};
  }
  if (tid == 0) {
    new_xyz[((size_t)b * NS) * 3 + 0] = sx[0];
    new_xyz[((size_t)b * NS) * 3 + 1] = sy[0];
    new_xyz[((size_t)b * NS) * 3 + 2] = sz[0];
  }

  const int lane = tid & 63;
  const int wave = tid >> 6;
  const unsigned nbase = ~(unsigned)base;
  int last = 0, buf = 0;

  for (int it = 1; it < NS; ++it) {
    float qx = sx[last], qy = sy[last], qz = sz[last];
    // packed distance update: v_pk_sub/mul/add, contract(off) keeps mul+add
#pragma unroll
    for (int k = 0; k < 8; ++k) {
      v2f dx = px[k] - qx;
      v2f dy = py[k] - qy;
      v2f dz = pz[k] - qz;
      v2f d2 = (dx * dx + dy * dy) + dz * dz;
      di[k] = __builtin_elementwise_min(di[k], d2);
    }
    // packed max tree -> scalar block max of this lane
    v2f m0 = __builtin_elementwise_max(di[0], di[1]);
    v2f m1 = __builtin_elementwise_max(di[2], di[3]);
    v2f m2 = __builtin_elementwise_max(di[4], di[5]);
    v2f m3 = __builtin_elementwise_max(di[6], di[7]);
    v2f m4 = __builtin_elementwise_max(m0, m1);
    v2f m5 = __builtin_elementwise_max(m2, m3);
    v2f m6 = __builtin_elementwise_max(m4, m5);
    float bd = fmaxf(m6.x, m6.y);
    // lowest-j recovery (descending scan: final bj = smallest matching j)
    int bj = 0;
#pragma unroll
    for (int j = 15; j >= 0; --j) {
      float v = (j & 1) ? di[j >> 1].y : di[j >> 1].x;
      if (v == bd) bj = j;
    }
    // pack (dist, index): u64 max == lexicographic (dist, -idx) max.
    unsigned long long key =
        ((unsigned long long)__float_as_uint(bd) << 32) |
        (unsigned)(nbase - (unsigned)bj);
    // wave-level max via DPP: row_shr 1/2/4/8, bcast15, bcast31 -> lane63
    DPP_KEYMAX(key, 0x111);
    DPP_KEYMAX(key, 0x112);
    DPP_KEYMAX(key, 0x114);
    DPP_KEYMAX(key, 0x118);
    DPP_KEYMAX(key, 0x142);
    DPP_KEYMAX(key, 0x143);
    if (lane == 63) rk[buf * 16 + wave] = key;
    __syncthreads();
    // cross-wave: 8 partials (+8 zero pads); 4 DPP steps into lane 15
    key = rk[buf * 16 + (lane & 15)];
    DPP_KEYMAX(key, 0x111);
    DPP_KEYMAX(key, 0x112);
    DPP_KEYMAX(key, 0x114);
    DPP_KEYMAX(key, 0x118);
    int fi = (int)~(unsigned)__builtin_amdgcn_readlane((int)(unsigned)key, 15);
    last = fi;
    buf ^= 1;
    if (tid == 0) {
      new_xyz[((size_t)b * NS + it) * 3 + 0] = sx[fi];
      new_xyz[((size_t)b * NS + it) * 3 + 1] = sy[fi];
      new_xyz[((size_t)b * NS + it) * 3 + 2] = sz[fi];
    }
  }
}

// ---------------------------------------------------------------------------
// Kernel 1: blocks 0..1023 = feature transpose (B,C,N)->(B,N,C) 64x64 tiles;
//           block 1024    = weight transpose to [c][o] layout.
// ---------------------------------------------------------------------------
__global__ __launch_bounds__(256)
void k_tp(const float* __restrict__ feat, const float* __restrict__ w0,
          const float* __restrict__ w1, const float* __restrict__ w2,
          float* __restrict__ featT, float* __restrict__ wT) {
  __shared__ float tile[64 * 65];
  const int tid = threadIdx.x;
  if (blockIdx.x < NB * (NPTS / 64)) {
    const int t = blockIdx.x;
    const int b = t >> 7;           // t / 128
    const int n0 = (t & 127) << 6;  // *64
    const int col = tid & 63;
    const int r0 = tid >> 6;  // 0..3
#pragma unroll
    for (int q = 0; q < 16; ++q) {
      int c = r0 + q * 4;
      tile[c * 65 + col] = feat[((size_t)b * NC_FEAT + c) * NPTS + n0 + col];
    }
    __syncthreads();
#pragma unroll
    for (int q = 0; q < 16; ++q) {
      int r = r0 + q * 4;
      featT[((size_t)b * NPTS + n0 + r) * 64 + col] = tile[col * 65 + r];
    }
  } else {
    for (int i = tid; i < 67 * 64; i += 256)
      wT[i] = w0[(i & 63) * 67 + (i >> 6)];
    for (int i = tid; i < 64 * 64; i += 256)
      wT[67 * 64 + i] = w1[(i & 63) * 64 + (i >> 6)];
    for (int i = tid; i < 64 * 128; i += 256)
      wT[67 * 64 + 64 * 64 + i] = w2[(i & 127) * 64 + (i >> 7)];
  }
}

// ---------------------------------------------------------------------------
// Kernel 2: ball query. One wave per query point; first-32-hits via ballot.
// ---------------------------------------------------------------------------
__global__ __launch_bounds__(256)
void k_ball(const float* __restrict__ pos, const float* __restrict__ nxyz,
            int* __restrict__ ballidx) {
  const int wid = (blockIdx.x * 256 + threadIdx.x) >> 6;  // global wave id
  const int lane = threadIdx.x & 63;
  const int b = wid >> 11;
  const float qx = nxyz[wid * 3 + 0];
  const float qy = nxyz[wid * 3 + 1];
  const float qz = nxyz[wid * 3 + 2];
  const float* p = pos + (size_t)b * NPTS * 3;
  int* outp = ballidx + (size_t)wid * NK;

  int cnt = 0;
  int firstidx = 0x7fffffff;
  for (int n0 = 0; n0 < NPTS; n0 += 64) {
    const int i = n0 + lane;
    float d2 = d2_ref(p[3 * i], p[3 * i + 1], p[3 * i + 2], qx, qy, qz);
    bool hit = d2 < 0.25f;
    unsigned long long mask = __ballot(hit);
    int pre = __popcll(mask & ((1ull << lane) - 1ull));
    int slot = cnt + pre;
    if (hit && slot < NK) outp[slot] = i;
    if (hit && slot == 0) firstidx = i;
    cnt += __popcll(mask);
    if (cnt >= NK) break;
  }
#pragma unroll
  for (int m = 32; m >= 1; m >>= 1)
    firstidx = min(firstidx, __shfl_xor(firstidx, m, 64));
  int pad = (firstidx == 0x7fffffff) ? 0 : firstidx;
  int start = cnt < NK ? cnt : NK;
  if (lane < NK && lane >= start) outp[lane] = pad;
}

// ---------------------------------------------------------------------------
// Kernel 3: gather + 3-layer MLP + max over k. One thread per (b,s,k) sample.
// Per-thread column in LDS (stride 256 -> conflict-free), weights read as
// wave-uniform float4 broadcasts from pre-transposed wT.
// ---------------------------------------------------------------------------
#define MLP_FMA16(wr, xc, acc)                                   \
  _Pragma("unroll") for (int o4 = 0; o4 < 16; ++o4) {            \
    float4 w = (wr)[o4];                                         \
    (acc)[o4 * 4 + 0] = fmaf(w.x, (xc), (acc)[o4 * 4 + 0]);      \
    (acc)[o4 * 4 + 1] = fmaf(w.y, (xc), (acc)[o4 * 4 + 1]);      \
    (acc)[o4 * 4 + 2] = fmaf(w.z, (xc), (acc)[o4 * 4 + 2]);      \
    (acc)[o4 * 4 + 3] = fmaf(w.w, (xc), (acc)[o4 * 4 + 3]);      \
  }

__global__ __launch_bounds__(256)
void k_mlp(const float* __restrict__ pos, const float* __restrict__ featT,
           const float* __restrict__ wT, const float* __restrict__ b0,
           const float* __restrict__ b1, const float* __restrict__ b2,
           const int* __restrict__ ballidx, const float* __restrict__ nxyz,
           float* __restrict__ outf) {
  __shared__ float xs[64 * 256];  // 64 KB: per-thread column, stride 256
  const int tid = threadIdx.x;
  const int g = blockIdx.x * 256 + tid;
  const int s = (g >> 5) & (NS - 1);
  const int b = g >> 16;

  const int idx = ballidx[g];
  const float qx = nxyz[((size_t)b * NS + s) * 3 + 0];
  const float qy = nxyz[((size_t)b * NS + s) * 3 + 1];
  const float qz = nxyz[((size_t)b * NS + s) * 3 + 2];
  const float* pp = pos + ((size_t)b * NPTS + idx) * 3;
  const float x0 = __fsub_rn(pp[0], qx);
  const float x1 = __fsub_rn(pp[1], qy);
  const float x2 = __fsub_rn(pp[2], qz);

  const float4* fT = (const float4*)(featT + ((size_t)b * NPTS + idx) * 64);
#pragma unroll
  for (int c4 = 0; c4 < 16; ++c4) {
    float4 v = fT[c4];
    xs[(c4 * 4 + 0) * 256 + tid] = v.x;
    xs[(c4 * 4 + 1) * 256 + tid] = v.y;
    xs[(c4 * 4 + 2) * 256 + tid] = v.z;
    xs[(c4 * 4 + 3) * 256 + tid] = v.w;
  }

  const float* wt0 = wT;
  const float* wt1 = wT + 67 * 64;
  const float* wt2 = wT + 67 * 64 + 64 * 64;

  float acc[64];
  // ---------------- layer 0: 67 -> 64 ----------------
#pragma unroll
  for (int o = 0; o < 64; ++o) acc[o] = b0[o];
  {
    const float xr0 = x0, xr1 = x1, xr2 = x2;
    const float4* wr;
    wr = (const float4*)(wt0 + 0 * 64); MLP_FMA16(wr, xr0, acc);
    wr = (const float4*)(wt0 + 1 * 64); MLP_FMA16(wr, xr1, acc);
    wr = (const float4*)(wt0 + 2 * 64); MLP_FMA16(wr, xr2, acc);
  }
  for (int c = 0; c < 64; ++c) {
    float xc = xs[c * 256 + tid];
    const float4* wr = (const float4*)(wt0 + (3 + c) * 64);
    MLP_FMA16(wr, xc, acc);
  }
#pragma unroll
  for (int o = 0; o < 64; ++o) xs[o * 256 + tid] = fmaxf(acc[o], 0.0f);

  // ---------------- layer 1: 64 -> 64 ----------------
#pragma unroll
  for (int o = 0; o < 64; ++o) acc[o] = b1[o];
  for (int c = 0; c < 64; ++c) {
    float xc = xs[c * 256 + tid];
    const float4* wr = (const float4*)(wt1 + c * 64);
    MLP_FMA16(wr, xc, acc);
  }
#pragma unroll
  for (int o = 0; o < 64; ++o) xs[o * 256 + tid] = fmaxf(acc[o], 0.0f);

  // ---------------- layer 2: 64 -> 128 (two halves) + max over k ----------
#pragma unroll
  for (int h = 0; h < 2; ++h) {
#pragma unroll
    for (int o = 0; o < 64; ++o) acc[o] = b2[h * 64 + o];
    for (int c = 0; c < 64; ++c) {
      float xc = xs[c * 256 + tid];
      const float4* wr = (const float4*)(wt2 + c * 128 + h * 64);
      MLP_FMA16(wr, xc, acc);
    }
#pragma unroll
    for (int o = 0; o < 64; ++o) {
      float v = fmaxf(acc[o], 0.0f);
      v = fmaxf(v, __shfl_xor(v, 16, 64));
      v = fmaxf(v, __shfl_xor(v, 8, 64));
      v = fmaxf(v, __shfl_xor(v, 4, 64));
      v = fmaxf(v, __shfl_xor(v, 2, 64));
      v = fmaxf(v, __shfl_xor(v, 1, 64));
      if ((tid & 31) == 0)
        outf[((size_t)b * 128 + h * 64 + o) * NS + s] = v;
    }
  }
}

// ---------------------------------------------------------------------------
extern "C" void kernel_launch(void* const* d_in, const int* in_sizes, int n_in,
                              void* d_out, int out_size, void* d_ws,
                              size_t ws_size, hipStream_t stream) {
  const float* pos = (const float*)d_in[0];
  const float* feat = (const float*)d_in[1];
  const float* w0 = (const float*)d_in[2];
  const float* b0 = (const float*)d_in[3];
  const float* w1 = (const float*)d_in[4];
  const float* b1 = (const float*)d_in[5];
  const float* w2 = (const float*)d_in[6];
  const float* b2 = (const float*)d_in[7];

  float* out = (float*)d_out;
  float* new_xyz = out;                         // (B, S, 3)
  float* new_feat = out + (size_t)NB * NS * 3;  // (B, 128, S)

  int* ballidx = (int*)d_ws;                                    // B*S*K ints
  float* featT = (float*)d_ws + (size_t)NB * NS * NK;           // B*N*64
  float* wT = featT + (size_t)NB * NPTS * 64;                   // 16576 floats

  // transpose (featT, wT) -- tiny, independent of FPS
  hipLaunchKernelGGL(k_tp, dim3(NB * (NPTS / 64) + 1), dim3(256), 0, stream,
                     feat, w0, w1, w2, featT, wT);
  // FPS: one 512-thread block per batch
  hipLaunchKernelGGL(k_fps, dim3(NB), dim3(512), 0, stream, pos, new_xyz);
  // ball query: one wave per (b,s)
  hipLaunchKernelGGL(k_ball, dim3((NB * NS) / 4), dim3(256), 0, stream, pos,
                     new_xyz, ballidx);
  // gather + MLP + max-k
  hipLaunchKernelGGL(k_mlp, dim3((NB * NS * NK) / 256), dim3(256), 0, stream,
                     pos, featT, wT, b0, b1, b2, ballidx, new_xyz, new_feat);
}